// Round 1
// baseline (224.358 us; speedup 1.0000x reference)
//
#include <hip/hip_runtime.h>
#include <math.h>

// CapsuleLayer dynamic routing, MI355X.
// B=128, R=4096, IN=16, OUT=32, C=2, 3 routing iterations.
#define CB   128
#define CR   4096
#define CIN  16
#define COUT 32
#define CCAP 2
#define RT   32          // r rows per kernel1 block
#define K1T  1024
#define K2T  512
#define EPSF 1e-12f

typedef _Float16 h8  __attribute__((ext_vector_type(8)));
typedef float    f8v __attribute__((ext_vector_type(8)));

// ---------------------------------------------------------------------------
// Kernel 1: priors[c][b][r][o] = sum_i x[b][r][i] * W[c][r][i][o]  (fp16 out)
// plus deterministic s0 partials: s0p[c][rt*4+rsub][b][o] = sum over this
// thread's 8 r-rows of priors (f32), so kernel2 can form s0 without atomics.
// grid = C*128 blocks (c, 32-row r-tile), 1024 threads.
// Thread map: rsub = t>>8 (which of 4 r's per staging round),
//             b = (t&255)>>1, og = t&1 (o-halves) -> W LDS reads are 2-way
//             broadcast (free), priors writes are 16B/lane contiguous pairs.
// ---------------------------------------------------------------------------
__global__ __launch_bounds__(K1T) void caps_priors_kernel(
    const float* __restrict__ x, const float* __restrict__ w,
    _Float16* __restrict__ priors, float* __restrict__ s0p)
{
  const int c    = (int)(blockIdx.x >> 7);
  const int rt   = (int)(blockIdx.x & 127);
  const int r0   = rt * RT;
  const int t    = (int)threadIdx.x;
  const int rsub = t >> 8;        // 0..3
  const int tt   = t & 255;
  const int b    = tt >> 1;       // 0..127
  const int og   = tt & 1;
  const int o0   = og * 16;

  __shared__ __align__(16) float Wl[4 * CIN * COUT];   // 4 W-rows, 8 KB

  float s0a[16];
#pragma unroll
  for (int j = 0; j < 16; ++j) s0a[j] = 0.f;

  for (int rr = 0; rr < RT / 4; ++rr) {
    const int rbase = r0 + rr * 4;
    __syncthreads();
    {
      // 4 consecutive W rows are contiguous: 2048 floats, 2 per thread.
      const float* wp = w + ((size_t)c * CR + rbase) * (CIN * COUT);
      Wl[t]        = wp[t];
      Wl[t + 1024] = wp[t + 1024];
    }
    __syncthreads();

    const int r = rbase + rsub;
    const float4* xp = (const float4*)(x + ((size_t)b * CR + r) * CIN);
    float4 x0 = xp[0], x1 = xp[1], x2 = xp[2], x3 = xp[3];
    float xs[16] = {x0.x, x0.y, x0.z, x0.w, x1.x, x1.y, x1.z, x1.w,
                    x2.x, x2.y, x2.z, x2.w, x3.x, x3.y, x3.z, x3.w};

    float p[16];
#pragma unroll
    for (int j = 0; j < 16; ++j) p[j] = 0.f;

    const float* wrow = &Wl[rsub * (CIN * COUT) + o0];
#pragma unroll
    for (int i = 0; i < 16; ++i) {
      const float4* wl4 = (const float4*)(wrow + i * COUT);
      float4 w0 = wl4[0], w1 = wl4[1], w2 = wl4[2], w3 = wl4[3];
      const float xi = xs[i];
      p[0]  += xi * w0.x;  p[1]  += xi * w0.y;  p[2]  += xi * w0.z;  p[3]  += xi * w0.w;
      p[4]  += xi * w1.x;  p[5]  += xi * w1.y;  p[6]  += xi * w1.z;  p[7]  += xi * w1.w;
      p[8]  += xi * w2.x;  p[9]  += xi * w2.y;  p[10] += xi * w2.z;  p[11] += xi * w2.w;
      p[12] += xi * w3.x;  p[13] += xi * w3.y;  p[14] += xi * w3.z;  p[15] += xi * w3.w;
    }

    h8 ha, hb;
#pragma unroll
    for (int j = 0; j < 8; ++j) { ha[j] = (_Float16)p[j]; hb[j] = (_Float16)p[j + 8]; }
#pragma unroll
    for (int j = 0; j < 16; ++j) s0a[j] += p[j];

    _Float16* pr = priors + (((size_t)(c * CB + b)) * CR + r) * COUT + o0;
    ((h8*)pr)[0] = ha;
    ((h8*)pr)[1] = hb;
  }

  const int rtp = rt * 4 + rsub;   // 0..511
  float* sp = s0p + (((size_t)c * 512 + rtp) * CB + b) * COUT + o0;
#pragma unroll
  for (int j = 0; j < 16; ++j) sp[j] = s0a[j];
}

// ---------------------------------------------------------------------------
// Kernel 2: routing. One block per (c,b) — 256 blocks, 512 threads.
// Thread t owns rows r = t + q*512, q=0..7: logits live in 8 registers.
// No softmax max-subtraction needed (|logits| < ||priors_row|| since
// ||squash|| < 1), so delta + exp + esum + weighted-s fuse into ONE pass
// over the 256KB priors row per iteration (2 passes total).
// ---------------------------------------------------------------------------

// block reduce: sums acc[0..31] and esum across 512 threads into sfin[0..32]
#define BLK_REDUCE()                                                        \
  do {                                                                      \
    _Pragma("unroll")                                                       \
    for (int sh_ = 1; sh_ < 64; sh_ <<= 1) {                                \
      _Pragma("unroll")                                                     \
      for (int o_ = 0; o_ < 32; ++o_) acc[o_] += __shfl_xor(acc[o_], sh_);  \
      esum += __shfl_xor(esum, sh_);                                        \
    }                                                                       \
    if (lane == 0) {                                                        \
      _Pragma("unroll")                                                     \
      for (int o_ = 0; o_ < 32; ++o_) red[wid][o_] = acc[o_];               \
      red[wid][32] = esum;                                                  \
    }                                                                       \
    __syncthreads();                                                        \
    if (t < 33) {                                                           \
      float s_ = red[0][t];                                                 \
      _Pragma("unroll")                                                     \
      for (int w_ = 1; w_ < 8; ++w_) s_ += red[w_][t];                      \
      sfin[t] = s_;                                                         \
    }                                                                       \
    __syncthreads();                                                        \
  } while (0)

__global__ __launch_bounds__(K2T) void caps_route_kernel(
    const _Float16* __restrict__ priors, const float* __restrict__ s0p,
    float* __restrict__ out)
{
  const int cb   = (int)blockIdx.x;       // c*128 + b
  const int c    = cb >> 7;
  const int b    = cb & 127;
  const int t    = (int)threadIdx.x;
  const int wid  = t >> 6;
  const int lane = t & 63;

  __shared__ float red[8][33];
  __shared__ float sfin[33];

  const _Float16* __restrict__ pb = priors + (size_t)cb * (CR * COUT);

  float acc[32], v[32], esum;
  float lg[8];   // this thread's logits for rows t + q*512

  // ---- Pass A: s0[o] = sum over 512 partials; v0 = squash(s0 / R) ----
  {
    const float4* sp4 =
        (const float4*)(s0p + (((size_t)c * 512 + t) * CB + b) * COUT);
#pragma unroll
    for (int q = 0; q < 8; ++q) {
      float4 vv = sp4[q];
      acc[4 * q + 0] = vv.x; acc[4 * q + 1] = vv.y;
      acc[4 * q + 2] = vv.z; acc[4 * q + 3] = vv.w;
    }
  }
  esum = 0.f;
  BLK_REDUCE();
  {
    float sn = 0.f;
#pragma unroll
    for (int o = 0; o < 32; ++o) { float s = sfin[o] * (1.f / CR); sn += s * s; }
    float fac = sn / ((1.f + sn + EPSF) * sqrtf(sn + EPSF));
#pragma unroll
    for (int o = 0; o < 32; ++o) v[o] = sfin[o] * (1.f / CR) * fac;
  }

  // ---- 2 fused routing iterations ----
#pragma unroll 1
  for (int it = 0; it < 2; ++it) {
#pragma unroll
    for (int o = 0; o < 32; ++o) acc[o] = 0.f;
    esum = 0.f;

#pragma unroll
    for (int q = 0; q < 8; ++q) {
      const int r = t + q * K2T;
      const h8* pr = (const h8*)(pb + (size_t)r * COUT);
      h8 a0 = pr[0], a1 = pr[1], a2 = pr[2], a3 = pr[3];
      f8v f0 = __builtin_convertvector(a0, f8v);
      f8v f1 = __builtin_convertvector(a1, f8v);
      f8v f2 = __builtin_convertvector(a2, f8v);
      f8v f3 = __builtin_convertvector(a3, f8v);

      float d = 0.f;
#pragma unroll
      for (int k = 0; k < 8; ++k)
        d += f0[k] * v[k] + f1[k] * v[k + 8] + f2[k] * v[k + 16] + f3[k] * v[k + 24];

      const float L = (it == 0) ? d : (lg[q] + d);
      lg[q] = L;
      const float e = __expf(L);   // safe: |L| < ||p_row|| * ||v|| < ~60
      esum += e;
#pragma unroll
      for (int k = 0; k < 8; ++k) {
        acc[k]      += e * f0[k];
        acc[k + 8]  += e * f1[k];
        acc[k + 16] += e * f2[k];
        acc[k + 24] += e * f3[k];
      }
    }

    BLK_REDUCE();

    if (it == 0) {
      float inv = 1.f / sfin[32];
      float sn = 0.f;
#pragma unroll
      for (int o = 0; o < 32; ++o) { float s = sfin[o] * inv; sn += s * s; }
      float fac = sn / ((1.f + sn + EPSF) * sqrtf(sn + EPSF));
#pragma unroll
      for (int o = 0; o < 32; ++o) v[o] = sfin[o] * inv * fac;
    }
  }

  // ---- output = squash(s2), s2[o] = sfin[o]/sfin[32] ----
  {
    float inv = 1.f / sfin[32];
    float sn = 0.f;
#pragma unroll
    for (int o = 0; o < 32; ++o) { float s = sfin[o] * inv; sn += s * s; }
    float fac = sn / ((1.f + sn + EPSF) * sqrtf(sn + EPSF));
    if (t < 32) out[(size_t)cb * COUT + t] = sfin[t] * inv * fac;
  }
}

extern "C" void kernel_launch(void* const* d_in, const int* in_sizes, int n_in,
                              void* d_out, int out_size, void* d_ws, size_t ws_size,
                              hipStream_t stream) {
  const float* x = (const float*)d_in[0];
  const float* w = (const float*)d_in[1];
  float* out = (float*)d_out;

  // workspace: priors fp16 (67.1 MB) then s0 partials f32 (16.8 MB)
  _Float16* priors = (_Float16*)d_ws;
  const size_t priors_bytes = (size_t)CCAP * CB * CR * COUT * sizeof(_Float16);
  float* s0p = (float*)((char*)d_ws + priors_bytes);

  caps_priors_kernel<<<dim3(CCAP * 128), K1T, 0, stream>>>(x, w, priors, s0p);
  caps_route_kernel<<<dim3(CCAP * CB), K2T, 0, stream>>>(priors, s0p, out);
}

// Round 2
// 93.384 us; speedup vs baseline: 2.4025x; 2.4025x over previous
//
#include <hip/hip_runtime.h>
#include <math.h>

// CapsuleLayer dynamic routing, MI355X.
// B=128, R=4096, IN=16, OUT=32, C=2, 3 routing iterations.
// Structure: K1 priors GEMM (+ s0 partials) -> red0 (v0) ->
//            pass(v0) -> red(v0+v1) -> pass(v0+v1) -> red(out).
// Logits never stored: L_k = p . Vsum_k (linear in the running v sum).
#define CB   128
#define CR   4096
#define CIN  16
#define COUT 32
#define CCAP 2
#define RT   32          // r rows per kernel1 block
#define K1T  1024
#define NCH  8           // r-chunks per (c,b) in pass kernels
#define EPSF 1e-12f

typedef _Float16 h8  __attribute__((ext_vector_type(8)));
typedef float    f8v __attribute__((ext_vector_type(8)));

// ---------------------------------------------------------------------------
// Kernel 1: priors[c][b][r][o] = sum_i x[b][r][i] * W[c][r][i][o]  (fp16 out)
// plus s0 partials reduced over the block: s0p[c][rt][b][o] (4 MB).
// grid = C*128 blocks (c, 32-row r-tile), 1024 threads.
// ---------------------------------------------------------------------------
__global__ __launch_bounds__(K1T) void caps_priors_kernel(
    const float* __restrict__ x, const float* __restrict__ w,
    _Float16* __restrict__ priors, float* __restrict__ s0p)
{
  const int c    = (int)(blockIdx.x >> 7);
  const int rt   = (int)(blockIdx.x & 127);
  const int r0   = rt * RT;
  const int t    = (int)threadIdx.x;
  const int rsub = t >> 8;        // 0..3
  const int tt   = t & 255;
  const int b    = tt >> 1;       // 0..127
  const int og   = tt & 1;
  const int o0   = og * 16;

  __shared__ __align__(16) float Wl[4 * CIN * COUT];   // 8 KB
  __shared__ __align__(16) float S0l[4][256][16];      // 64 KB

  float s0a[16];
#pragma unroll
  for (int j = 0; j < 16; ++j) s0a[j] = 0.f;

  for (int rr = 0; rr < RT / 4; ++rr) {
    const int rbase = r0 + rr * 4;
    __syncthreads();
    {
      const float* wp = w + ((size_t)c * CR + rbase) * (CIN * COUT);
      Wl[t]        = wp[t];
      Wl[t + 1024] = wp[t + 1024];
    }
    __syncthreads();

    const int r = rbase + rsub;
    const float4* xp = (const float4*)(x + ((size_t)b * CR + r) * CIN);
    float4 x0 = xp[0], x1 = xp[1], x2 = xp[2], x3 = xp[3];
    float xs[16] = {x0.x, x0.y, x0.z, x0.w, x1.x, x1.y, x1.z, x1.w,
                    x2.x, x2.y, x2.z, x2.w, x3.x, x3.y, x3.z, x3.w};

    float p[16];
#pragma unroll
    for (int j = 0; j < 16; ++j) p[j] = 0.f;

    const float* wrow = &Wl[rsub * (CIN * COUT) + o0];
#pragma unroll
    for (int i = 0; i < 16; ++i) {
      const float4* wl4 = (const float4*)(wrow + i * COUT);
      float4 w0 = wl4[0], w1 = wl4[1], w2 = wl4[2], w3 = wl4[3];
      const float xi = xs[i];
      p[0]  += xi * w0.x;  p[1]  += xi * w0.y;  p[2]  += xi * w0.z;  p[3]  += xi * w0.w;
      p[4]  += xi * w1.x;  p[5]  += xi * w1.y;  p[6]  += xi * w1.z;  p[7]  += xi * w1.w;
      p[8]  += xi * w2.x;  p[9]  += xi * w2.y;  p[10] += xi * w2.z;  p[11] += xi * w2.w;
      p[12] += xi * w3.x;  p[13] += xi * w3.y;  p[14] += xi * w3.z;  p[15] += xi * w3.w;
    }

    h8 ha, hb;
#pragma unroll
    for (int j = 0; j < 8; ++j) { ha[j] = (_Float16)p[j]; hb[j] = (_Float16)p[j + 8]; }
#pragma unroll
    for (int j = 0; j < 16; ++j) s0a[j] += p[j];

    _Float16* pr = priors + (((size_t)(c * CB + b)) * CR + r) * COUT + o0;
    ((h8*)pr)[0] = ha;
    ((h8*)pr)[1] = hb;
  }

  // block-reduce s0 over rsub (4x) -> s0p[c][rt][b][o]
#pragma unroll
  for (int j = 0; j < 16; ++j) S0l[rsub][tt][j] = s0a[j];
  __syncthreads();
  if (t < 256) {
    const int bb = t >> 1, oo = (t & 1) * 16;
    float* sp = s0p + (((size_t)(c * 128 + rt)) * CB + bb) * COUT + oo;
#pragma unroll
    for (int j = 0; j < 16; ++j)
      sp[j] = S0l[0][t][j] + S0l[1][t][j] + S0l[2][t][j] + S0l[3][t][j];
  }
}

// ---------------------------------------------------------------------------
// red0: v0 = squash(mean_r priors) from s0p. grid 256 (c,b) x 256 threads.
// ---------------------------------------------------------------------------
__global__ __launch_bounds__(256) void caps_red0_kernel(
    const float* __restrict__ s0p, float* __restrict__ vsum)
{
  const int cb = (int)blockIdx.x;
  const int c  = cb >> 7, b = cb & 127;
  const int t  = (int)threadIdx.x;
  const int o  = t & 31, g = t >> 5;          // g = 0..7

  float s = 0.f;
#pragma unroll 4
  for (int j = g; j < 128; j += 8)
    s += s0p[(((size_t)(c * 128 + j)) * CB + b) * COUT + o];

  __shared__ float rg[8][32];
  rg[g][o] = s;
  __syncthreads();
  if (t < 32) {
    float s0 = rg[0][t] + rg[1][t] + rg[2][t] + rg[3][t] +
               rg[4][t] + rg[5][t] + rg[6][t] + rg[7][t];
    float sm = s0 * (1.f / (float)CR);
    float sn = sm * sm;
#pragma unroll
    for (int sh = 1; sh < 32; sh <<= 1) sn += __shfl_xor(sn, sh);
    float fac = sn / ((1.f + sn + EPSF) * sqrtf(sn + EPSF));
    vsum[cb * COUT + t] = sm * fac;
  }
}

// ---------------------------------------------------------------------------
// pass: for each row r of (c,b): e = exp(p . vsum); partial s = sum e*p, esum.
// grid = 256*NCH blocks, 256 threads, 2 rows/thread.
// partial[cb][ch][33]
// ---------------------------------------------------------------------------
__global__ __launch_bounds__(256) void caps_pass_kernel(
    const _Float16* __restrict__ priors, const float* __restrict__ vsum,
    float* __restrict__ partial)
{
  const int bid = (int)blockIdx.x;
  const int cb  = bid >> 3, ch = bid & (NCH - 1);
  const int t   = (int)threadIdx.x;
  const int wid = t >> 6, lane = t & 63;

  __shared__ __align__(16) float vl[32];
  __shared__ float rl[4][33];

  if (t < 32) vl[t] = vsum[cb * COUT + t];
  __syncthreads();

  float v[32];
#pragma unroll
  for (int k = 0; k < 8; ++k) {
    float4 vv = ((const float4*)vl)[k];
    v[4 * k] = vv.x; v[4 * k + 1] = vv.y; v[4 * k + 2] = vv.z; v[4 * k + 3] = vv.w;
  }

  float acc[32];
#pragma unroll
  for (int k = 0; k < 32; ++k) acc[k] = 0.f;
  float esum = 0.f;

#pragma unroll
  for (int q = 0; q < 2; ++q) {
    const int r = ch * 512 + q * 256 + t;
    const h8* pr = (const h8*)(priors + (((size_t)cb) * CR + r) * COUT);
    h8 a0 = pr[0], a1 = pr[1], a2 = pr[2], a3 = pr[3];
    f8v f0 = __builtin_convertvector(a0, f8v);
    f8v f1 = __builtin_convertvector(a1, f8v);
    f8v f2 = __builtin_convertvector(a2, f8v);
    f8v f3 = __builtin_convertvector(a3, f8v);

    float d = 0.f;
#pragma unroll
    for (int k = 0; k < 8; ++k)
      d += f0[k] * v[k] + f1[k] * v[k + 8] + f2[k] * v[k + 16] + f3[k] * v[k + 24];

    const float e = __expf(d);   // safe: |d| <= ||p_row|| * ||vsum|| < ~80
    esum += e;
#pragma unroll
    for (int k = 0; k < 8; ++k) {
      acc[k]      += e * f0[k];
      acc[k + 8]  += e * f1[k];
      acc[k + 16] += e * f2[k];
      acc[k + 24] += e * f3[k];
    }
  }

  // wave reduce then cross-wave via LDS
#pragma unroll
  for (int sh = 1; sh < 64; sh <<= 1) {
#pragma unroll
    for (int k = 0; k < 32; ++k) acc[k] += __shfl_xor(acc[k], sh);
    esum += __shfl_xor(esum, sh);
  }
  if (lane == 0) {
#pragma unroll
    for (int k = 0; k < 32; ++k) rl[wid][k] = acc[k];
    rl[wid][32] = esum;
  }
  __syncthreads();
  if (t < 33) {
    float s = rl[0][t] + rl[1][t] + rl[2][t] + rl[3][t];
    partial[(size_t)bid * 33 + t] = s;
  }
}

// ---------------------------------------------------------------------------
// redv: reduce partials -> v = squash(s/esum); vsum += v, or write out (final).
// grid 256 (c,b) x 64 threads.
// ---------------------------------------------------------------------------
__global__ __launch_bounds__(64) void caps_redv_kernel(
    const float* __restrict__ partial, float* __restrict__ vsum,
    float* __restrict__ out, int final_)
{
  const int cb = (int)blockIdx.x;
  const int t  = (int)threadIdx.x;
  __shared__ float sf[33];
  if (t < 33) {
    float s = 0.f;
#pragma unroll
    for (int j = 0; j < NCH; ++j) s += partial[((size_t)cb * NCH + j) * 33 + t];
    sf[t] = s;
  }
  __syncthreads();
  if (t < 32) {
    float inv = 1.f / sf[32];
    float sm = sf[t] * inv;
    float sn = sm * sm;
#pragma unroll
    for (int sh = 1; sh < 32; sh <<= 1) sn += __shfl_xor(sn, sh);
    float fac = sn / ((1.f + sn + EPSF) * sqrtf(sn + EPSF));
    float vv = sm * fac;
    if (final_) out[cb * COUT + t] = vv;
    else        vsum[cb * COUT + t] += vv;
  }
}

extern "C" void kernel_launch(void* const* d_in, const int* in_sizes, int n_in,
                              void* d_out, int out_size, void* d_ws, size_t ws_size,
                              hipStream_t stream) {
  const float* x = (const float*)d_in[0];
  const float* w = (const float*)d_in[1];
  float* out = (float*)d_out;

  char* p = (char*)d_ws;
  _Float16* priors = (_Float16*)p;                 // 67,108,864 B
  p += (size_t)CCAP * CB * CR * COUT * sizeof(_Float16);
  float* s0p = (float*)p;                          // 4,194,304 B
  p += (size_t)CCAP * 128 * CB * COUT * sizeof(float);
  float* vsum = (float*)p;                         // 32,768 B
  p += (size_t)CCAP * CB * COUT * sizeof(float);
  float* partial = (float*)p;                      // 270,336 B

  caps_priors_kernel<<<dim3(CCAP * 128), K1T, 0, stream>>>(x, w, priors, s0p);
  caps_red0_kernel<<<dim3(CCAP * CB), 256, 0, stream>>>(s0p, vsum);
  caps_pass_kernel<<<dim3(CCAP * CB * NCH), 256, 0, stream>>>(priors, vsum, partial);
  caps_redv_kernel<<<dim3(CCAP * CB), 64, 0, stream>>>(partial, vsum, out, 0);
  caps_pass_kernel<<<dim3(CCAP * CB * NCH), 256, 0, stream>>>(priors, vsum, partial);
  caps_redv_kernel<<<dim3(CCAP * CB), 64, 0, stream>>>(partial, vsum, out, 1);
}

// Round 3
// 91.337 us; speedup vs baseline: 2.4564x; 1.0224x over previous
//
#include <hip/hip_runtime.h>
#include <math.h>

// CapsuleLayer dynamic routing, MI355X.
// B=128, R=4096, IN=16, OUT=32, C=2, 3 routing iterations.
// K1 priors GEMM (+ fp16 s0 partials) -> red0 (v0) ->
// pass(v0) -> redv (vsum=v0+v1) -> pass(vsum) -> redv (out).
// Logits never stored: L_k = p . Vsum_k (linear in the running v sum).
#define CB   128
#define CR   4096
#define CIN  16
#define COUT 32
#define CCAP 2
#define RT   32          // r rows per kernel1 block
#define K1T  1024
#define NCH  8           // r-chunks per (c,b) in pass kernels
#define EPSF 1e-12f

typedef _Float16 h8  __attribute__((ext_vector_type(8)));
typedef float    f8v __attribute__((ext_vector_type(8)));

// ---------------------------------------------------------------------------
// Kernel 1: priors[c][b][r][o] = sum_i x[b][r][i] * W[c][r][i][o]  (fp16 out)
// plus per-thread s0 partials, fp16: s0p[c][rt*4+rsub][b][o].
// grid = C*128 blocks (c, 32-row r-tile), 1024 threads.
// NOTE: round-1-proven codegen shape. Do NOT add big LDS arrays here —
// a 64KB block-reduce epilogue in R2 collapsed VGPRs to 32 and made the
// whole kernel 4x slower (spill/recompute in the inner loop).
// ---------------------------------------------------------------------------
__global__ __launch_bounds__(K1T) void caps_priors_kernel(
    const float* __restrict__ x, const float* __restrict__ w,
    _Float16* __restrict__ priors, _Float16* __restrict__ s0p)
{
  const int c    = (int)(blockIdx.x >> 7);
  const int rt   = (int)(blockIdx.x & 127);
  const int r0   = rt * RT;
  const int t    = (int)threadIdx.x;
  const int rsub = t >> 8;        // 0..3
  const int tt   = t & 255;
  const int b    = tt >> 1;       // 0..127
  const int og   = tt & 1;
  const int o0   = og * 16;

  __shared__ __align__(16) float Wl[4 * CIN * COUT];   // 8 KB only

  float s0a[16];
#pragma unroll
  for (int j = 0; j < 16; ++j) s0a[j] = 0.f;

  for (int rr = 0; rr < RT / 4; ++rr) {
    const int rbase = r0 + rr * 4;
    __syncthreads();
    {
      // 4 consecutive W rows are contiguous: 2048 floats, 2 per thread.
      const float* wp = w + ((size_t)c * CR + rbase) * (CIN * COUT);
      Wl[t]        = wp[t];
      Wl[t + 1024] = wp[t + 1024];
    }
    __syncthreads();

    const int r = rbase + rsub;
    const float4* xp = (const float4*)(x + ((size_t)b * CR + r) * CIN);
    float4 x0 = xp[0], x1 = xp[1], x2 = xp[2], x3 = xp[3];
    float xs[16] = {x0.x, x0.y, x0.z, x0.w, x1.x, x1.y, x1.z, x1.w,
                    x2.x, x2.y, x2.z, x2.w, x3.x, x3.y, x3.z, x3.w};

    float p[16];
#pragma unroll
    for (int j = 0; j < 16; ++j) p[j] = 0.f;

    const float* wrow = &Wl[rsub * (CIN * COUT) + o0];
#pragma unroll
    for (int i = 0; i < 16; ++i) {
      const float4* wl4 = (const float4*)(wrow + i * COUT);
      float4 w0 = wl4[0], w1 = wl4[1], w2 = wl4[2], w3 = wl4[3];
      const float xi = xs[i];
      p[0]  += xi * w0.x;  p[1]  += xi * w0.y;  p[2]  += xi * w0.z;  p[3]  += xi * w0.w;
      p[4]  += xi * w1.x;  p[5]  += xi * w1.y;  p[6]  += xi * w1.z;  p[7]  += xi * w1.w;
      p[8]  += xi * w2.x;  p[9]  += xi * w2.y;  p[10] += xi * w2.z;  p[11] += xi * w2.w;
      p[12] += xi * w3.x;  p[13] += xi * w3.y;  p[14] += xi * w3.z;  p[15] += xi * w3.w;
    }

    h8 ha, hb;
#pragma unroll
    for (int j = 0; j < 8; ++j) { ha[j] = (_Float16)p[j]; hb[j] = (_Float16)p[j + 8]; }
#pragma unroll
    for (int j = 0; j < 16; ++j) s0a[j] += p[j];

    _Float16* pr = priors + (((size_t)(c * CB + b)) * CR + r) * COUT + o0;
    ((h8*)pr)[0] = ha;
    ((h8*)pr)[1] = hb;
  }

  // fp16-packed partial store — same conversion/store pattern as priors.
  const int rtp = rt * 4 + rsub;   // 0..511
  h8 sa, sb;
#pragma unroll
  for (int j = 0; j < 8; ++j) { sa[j] = (_Float16)s0a[j]; sb[j] = (_Float16)s0a[j + 8]; }
  _Float16* sp = s0p + (((size_t)c * 512 + rtp) * CB + b) * COUT + o0;
  ((h8*)sp)[0] = sa;
  ((h8*)sp)[1] = sb;
}

// ---------------------------------------------------------------------------
// red0: v0 = squash(mean_r priors) from fp16 s0p. grid 256 (c,b) x 256 thr.
// thread t: og8 = t&3 (8-wide o group), g = t>>2 (0..63); h8 vector loads.
// ---------------------------------------------------------------------------
__global__ __launch_bounds__(256) void caps_red0_kernel(
    const _Float16* __restrict__ s0p, float* __restrict__ vsum)
{
  const int cb  = (int)blockIdx.x;
  const int c   = cb >> 7, b = cb & 127;
  const int t   = (int)threadIdx.x;
  const int og8 = t & 3, g = t >> 2;

  float a8[8];
#pragma unroll
  for (int k = 0; k < 8; ++k) a8[k] = 0.f;

#pragma unroll
  for (int jj = 0; jj < 8; ++jj) {
    const int j = g + jj * 64;
    h8 v = *(const h8*)(s0p + (((size_t)c * 512 + j) * CB + b) * COUT + og8 * 8);
    f8v f = __builtin_convertvector(v, f8v);
#pragma unroll
    for (int k = 0; k < 8; ++k) a8[k] += f[k];
  }

  __shared__ float R[64][33];
#pragma unroll
  for (int k = 0; k < 8; ++k) R[g][og8 * 8 + k] = a8[k];
  __syncthreads();

  if (t < 32) {
    float s0 = 0.f;
#pragma unroll 8
    for (int gg = 0; gg < 64; ++gg) s0 += R[gg][t];
    float sm = s0 * (1.f / (float)CR);
    float sn = sm * sm;
#pragma unroll
    for (int sh = 1; sh < 32; sh <<= 1) sn += __shfl_xor(sn, sh);
    float fac = sn / ((1.f + sn + EPSF) * sqrtf(sn + EPSF));
    vsum[cb * COUT + t] = sm * fac;
  }
}

// ---------------------------------------------------------------------------
// pass: for each row r of (c,b): e = exp(p . vsum); partial s = sum e*p, esum.
// grid = 256*NCH blocks, 256 threads, 2 rows/thread. partial[cb][ch][33]
// ---------------------------------------------------------------------------
__global__ __launch_bounds__(256) void caps_pass_kernel(
    const _Float16* __restrict__ priors, const float* __restrict__ vsum,
    float* __restrict__ partial)
{
  const int bid = (int)blockIdx.x;
  const int cb  = bid >> 3, ch = bid & (NCH - 1);
  const int t   = (int)threadIdx.x;
  const int wid = t >> 6, lane = t & 63;

  __shared__ __align__(16) float vl[32];
  __shared__ float rl[4][33];

  if (t < 32) vl[t] = vsum[cb * COUT + t];
  __syncthreads();

  float v[32];
#pragma unroll
  for (int k = 0; k < 8; ++k) {
    float4 vv = ((const float4*)vl)[k];
    v[4 * k] = vv.x; v[4 * k + 1] = vv.y; v[4 * k + 2] = vv.z; v[4 * k + 3] = vv.w;
  }

  float acc[32];
#pragma unroll
  for (int k = 0; k < 32; ++k) acc[k] = 0.f;
  float esum = 0.f;

#pragma unroll
  for (int q = 0; q < 2; ++q) {
    const int r = ch * 512 + q * 256 + t;
    const h8* pr = (const h8*)(priors + (((size_t)cb) * CR + r) * COUT);
    h8 a0 = pr[0], a1 = pr[1], a2 = pr[2], a3 = pr[3];
    f8v f0 = __builtin_convertvector(a0, f8v);
    f8v f1 = __builtin_convertvector(a1, f8v);
    f8v f2 = __builtin_convertvector(a2, f8v);
    f8v f3 = __builtin_convertvector(a3, f8v);

    float d = 0.f;
#pragma unroll
    for (int k = 0; k < 8; ++k)
      d += f0[k] * v[k] + f1[k] * v[k + 8] + f2[k] * v[k + 16] + f3[k] * v[k + 24];

    const float e = __expf(d);   // safe: |d| <= ||p_row|| * ||vsum|| < ~80
    esum += e;
#pragma unroll
    for (int k = 0; k < 8; ++k) {
      acc[k]      += e * f0[k];
      acc[k + 8]  += e * f1[k];
      acc[k + 16] += e * f2[k];
      acc[k + 24] += e * f3[k];
    }
  }

  // wave reduce then cross-wave via LDS
#pragma unroll
  for (int sh = 1; sh < 64; sh <<= 1) {
#pragma unroll
    for (int k = 0; k < 32; ++k) acc[k] += __shfl_xor(acc[k], sh);
    esum += __shfl_xor(esum, sh);
  }
  if (lane == 0) {
#pragma unroll
    for (int k = 0; k < 32; ++k) rl[wid][k] = acc[k];
    rl[wid][32] = esum;
  }
  __syncthreads();
  if (t < 33) {
    float s = rl[0][t] + rl[1][t] + rl[2][t] + rl[3][t];
    partial[(size_t)bid * 33 + t] = s;
  }
}

// ---------------------------------------------------------------------------
// redv: reduce partials -> v = squash(s/esum); vsum += v, or write out (final).
// grid 256 (c,b) x 64 threads.
// ---------------------------------------------------------------------------
__global__ __launch_bounds__(64) void caps_redv_kernel(
    const float* __restrict__ partial, float* __restrict__ vsum,
    float* __restrict__ out, int final_)
{
  const int cb = (int)blockIdx.x;
  const int t  = (int)threadIdx.x;
  __shared__ float sf[33];
  if (t < 33) {
    float s = 0.f;
#pragma unroll
    for (int j = 0; j < NCH; ++j) s += partial[((size_t)cb * NCH + j) * 33 + t];
    sf[t] = s;
  }
  __syncthreads();
  if (t < 32) {
    float inv = 1.f / sf[32];
    float sm = sf[t] * inv;
    float sn = sm * sm;
#pragma unroll
    for (int sh = 1; sh < 32; sh <<= 1) sn += __shfl_xor(sn, sh);
    float fac = sn / ((1.f + sn + EPSF) * sqrtf(sn + EPSF));
    float vv = sm * fac;
    if (final_) out[cb * COUT + t] = vv;
    else        vsum[cb * COUT + t] += vv;
  }
}

extern "C" void kernel_launch(void* const* d_in, const int* in_sizes, int n_in,
                              void* d_out, int out_size, void* d_ws, size_t ws_size,
                              hipStream_t stream) {
  const float* x = (const float*)d_in[0];
  const float* w = (const float*)d_in[1];
  float* out = (float*)d_out;

  char* p = (char*)d_ws;
  _Float16* priors = (_Float16*)p;                 // 67,108,864 B
  p += (size_t)CCAP * CB * CR * COUT * sizeof(_Float16);
  _Float16* s0p = (_Float16*)p;                    // 8,388,608 B (fp16 now)
  p += (size_t)CCAP * 512 * CB * COUT * sizeof(_Float16);
  float* vsum = (float*)p;                         // 32,768 B
  p += (size_t)CCAP * CB * COUT * sizeof(float);
  float* partial = (float*)p;                      // 270,336 B
  // total 75,800,576 B — under the 83.9 MB proven available in round 1.

  caps_priors_kernel<<<dim3(CCAP * 128), K1T, 0, stream>>>(x, w, priors, s0p);
  caps_red0_kernel<<<dim3(CCAP * CB), 256, 0, stream>>>(s0p, vsum);
  caps_pass_kernel<<<dim3(CCAP * CB * NCH), 256, 0, stream>>>(priors, vsum, partial);
  caps_redv_kernel<<<dim3(CCAP * CB), 64, 0, stream>>>(partial, vsum, out, 0);
  caps_pass_kernel<<<dim3(CCAP * CB * NCH), 256, 0, stream>>>(priors, vsum, partial);
  caps_redv_kernel<<<dim3(CCAP * CB), 64, 0, stream>>>(partial, vsum, out, 1);
}